// Round 7
// baseline (3064.817 us; speedup 1.0000x reference)
//
#include <hip/hip_runtime.h>

#define N_NODES 100000
#define N_EDGES 1600000
#define FEAT 256
#define KTOT 512
#define NBUCK ((N_NODES + 63) / 64)       // 1563 buckets of 64 dst-nodes

typedef __attribute__((ext_vector_type(8))) short short8v;     // 8 bf16 = 4 VGPRs
typedef __attribute__((ext_vector_type(4))) float f32x4;
typedef __attribute__((ext_vector_type(4))) unsigned short ushort4v;

__device__ __forceinline__ unsigned short f2bf(float f) {
    unsigned u = __float_as_uint(f);
    return (unsigned short)((u + 0x7FFFu + ((u >> 16) & 1u)) >> 16);   // RNE
}
__device__ __forceinline__ float bf2f(unsigned short s) {
    return __uint_as_float(((unsigned)s) << 16);
}
__device__ __forceinline__ short8v zero8() {
    short8v v;
    #pragma unroll
    for (int i = 0; i < 8; ++i) v[i] = 0;
    return v;
}

// ---------------- workspace layout ----------------
// xh  : [N][512] bf16  — cols 0:256 = z (aggregated), 256:512 = bf16(h)
// Bt  : [256][512] bf16
// seg_cnt/seg_base/seg_cur : [NBUCK+1] int (padded to 8 KB each)
// bin : [N_EDGES] u32 packed (ln<<20 | src), grouped by bucket
constexpr size_t OFF_XH   = 0;
constexpr size_t XH_BYTES = (size_t)N_NODES * KTOT * 2;        // 102,400,000
constexpr size_t OFF_BT   = XH_BYTES;
constexpr size_t OFF_SEGC = OFF_BT + 262144;
constexpr size_t OFF_SEGB = OFF_SEGC + 8192;
constexpr size_t OFF_SEGU = OFF_SEGB + 8192;
constexpr size_t OFF_BIN  = OFF_SEGU + 8192;
constexpr size_t WS_NEEDED = OFF_BIN + (size_t)N_EDGES * 4;    // ~109.1 MB

// ---------------- prep kernels ----------------
__global__ __launch_bounds__(256) void cast_h_kernel(
    const float* __restrict__ h, unsigned short* __restrict__ xh)
{
    int tid = blockIdx.x * 256 + threadIdx.x;
    int row = tid >> 5;
    int c8  = (tid & 31) * 8;
    const float4* p = (const float4*)&h[(size_t)row * FEAT + c8];
    float4 a = p[0], b = p[1];
    unsigned short tmp[8];
    tmp[0]=f2bf(a.x); tmp[1]=f2bf(a.y); tmp[2]=f2bf(a.z); tmp[3]=f2bf(a.w);
    tmp[4]=f2bf(b.x); tmp[5]=f2bf(b.y); tmp[6]=f2bf(b.z); tmp[7]=f2bf(b.w);
    *(short8v*)&xh[(size_t)row * KTOT + 256 + c8] = *(short8v*)tmp;
}

__global__ __launch_bounds__(256) void prep_b_kernel(
    const float* __restrict__ W, const float* __restrict__ res_w,
    unsigned short* __restrict__ Bt)
{
    int n = blockIdx.x, t = threadIdx.x;
    Bt[(size_t)n * KTOT + t]       = f2bf(W[(size_t)t * FEAT + n]);       // W^T
    Bt[(size_t)n * KTOT + 256 + t] = f2bf(res_w[(size_t)n * FEAT + t]);   // res_w
}

// ---------------- bucket binning ----------------
__global__ __launch_bounds__(256) void count_kernel(
    const int* __restrict__ dst, int* __restrict__ seg_cnt)
{
    int e = blockIdx.x * 256 + threadIdx.x;
    if (e < N_EDGES) atomicAdd(&seg_cnt[dst[e] >> 6], 1);
}

__global__ __launch_bounds__(1024) void scan_seg_kernel(
    const int* __restrict__ seg_cnt,
    int* __restrict__ seg_base, int* __restrict__ seg_cur)
{
    __shared__ int part[1024];
    const int t = threadIdx.x;
    int i0 = t * 2, i1 = t * 2 + 1;
    int v0 = (i0 < NBUCK) ? seg_cnt[i0] : 0;
    int v1 = (i1 < NBUCK) ? seg_cnt[i1] : 0;
    int s = v0 + v1;
    part[t] = s;
    __syncthreads();
    for (int d = 1; d < 1024; d <<= 1) {    // inclusive Hillis-Steele
        int u = (t >= d) ? part[t - d] : 0;
        __syncthreads();
        part[t] += u;
        __syncthreads();
    }
    int base = part[t] - s;                 // exclusive
    if (i0 < NBUCK) { seg_base[i0] = base;      seg_cur[i0] = base; }
    if (i1 < NBUCK) { seg_base[i1] = base + v0; seg_cur[i1] = base + v0; }
    if (t == 0) seg_base[NBUCK] = N_EDGES;
}

__global__ __launch_bounds__(256) void bin_kernel(
    const int* __restrict__ src, const int* __restrict__ dst,
    int* __restrict__ seg_cur, unsigned int* __restrict__ bin)
{
    int e = blockIdx.x * 256 + threadIdx.x;
    if (e < N_EDGES) {
        int d = dst[e];
        int p = atomicAdd(&seg_cur[d >> 6], 1);
        bin[p] = ((unsigned)(d & 63) << 20) | (unsigned)src[e];
    }
}

// ---------------- bucket aggregation in LDS ----------------
// z[n] = norm[n] * sum_{e: dst=n} norm[src_e] * bf16(h[src_e])
// one block per 64-node bucket; 64KB fp32 accumulator in LDS.
// lane l owns feats {l, l+64, l+128, l+192} -> LDS bank = l%32, conflict-free.
__global__ __launch_bounds__(512) void agg_bin_kernel(
    const float* __restrict__ norm,
    const int*   __restrict__ seg_base,
    const unsigned int* __restrict__ bin,
    unsigned short* __restrict__ xh)       // reads h half (+256), writes z half
{
    __shared__ float zb[64 * 256];         // 64 KB
    const int b = blockIdx.x;
    const int t = threadIdx.x;
    #pragma unroll
    for (int i = 0; i < 32; ++i) zb[i * 512 + t] = 0.f;
    const int lo = seg_base[b];
    const int hi = seg_base[b + 1];
    __syncthreads();

    const int wave = t >> 6, lane = t & 63;
    for (int e = lo + wave; e < hi; e += 8) {
        unsigned pk = bin[e];              // uniform across the wave
        int ln = pk >> 20;
        int s  = pk & 0xFFFFF;
        float m = norm[s];
        const unsigned short* hp = &xh[(size_t)s * KTOT + 256];
        float f0 = bf2f(hp[lane]);
        float f1 = bf2f(hp[lane + 64]);
        float f2 = bf2f(hp[lane + 128]);
        float f3 = bf2f(hp[lane + 192]);
        float* zrow = &zb[ln * 256];
        atomicAdd(&zrow[lane],       f0 * m);
        atomicAdd(&zrow[lane + 64],  f1 * m);
        atomicAdd(&zrow[lane + 128], f2 * m);
        atomicAdd(&zrow[lane + 192], f3 * m);
    }
    __syncthreads();

    // write out: thread t -> node row r = t>>3, feats (t&7)*32 .. +32
    int r = t >> 3;
    int n = b * 64 + r;
    if (n < N_NODES) {
        float nm = norm[n];
        int c0 = (t & 7) * 32;
        #pragma unroll
        for (int j = 0; j < 4; ++j) {
            unsigned short tmp[8];
            #pragma unroll
            for (int q = 0; q < 8; ++q)
                tmp[q] = f2bf(zb[r * 256 + c0 + j * 8 + q] * nm);
            *(short8v*)&xh[(size_t)n * KTOT + c0 + j * 8] = *(short8v*)tmp;
        }
    }
}

// ---------------- fused MFMA GEMM: out = relu(xh @ Bt^T + bias + res_b) ----------------
#define GBM 128
#define GBN 128
#define GBK 32
#define LDT 40   // shorts per LDS row = 80 B (16B-aligned, spreads banks)

__global__ __launch_bounds__(256) void mfma_gemm_kernel(
    const unsigned short* __restrict__ xh,   // A: [N][512] bf16
    const unsigned short* __restrict__ Bt,   // [256][512] bf16 (n-major)
    const float* __restrict__ bias,
    const float* __restrict__ res_b,
    float* __restrict__ out)
{
    __shared__ unsigned short As[GBM * LDT];
    __shared__ unsigned short Bs[GBN * LDT];
    const int t    = threadIdx.x;
    const int m0   = blockIdx.x * GBM;
    const int n0   = blockIdx.y * GBN;
    const int wave = t >> 6, lane = t & 63;
    const int wm   = wave >> 1, wn = wave & 1;
    const int lrow = lane & 15, kg = lane >> 4;

    f32x4 zf = {0.f, 0.f, 0.f, 0.f};
    f32x4 acc[4][4];
    #pragma unroll
    for (int i = 0; i < 4; ++i)
        #pragma unroll
        for (int j = 0; j < 4; ++j) acc[i][j] = zf;

    for (int k0 = 0; k0 < KTOT; k0 += GBK) {
        #pragma unroll
        for (int it = 0; it < 2; ++it) {
            int idx = it * 256 + t;
            int row = idx >> 2;
            int ch  = (idx & 3) * 8;
            int grow = m0 + row;
            short8v va = zero8();
            if (grow < N_NODES)
                va = *(const short8v*)&xh[(size_t)grow * KTOT + k0 + ch];
            *(short8v*)&As[row * LDT + ch] = va;
            short8v vb = *(const short8v*)&Bt[(size_t)(n0 + row) * KTOT + k0 + ch];
            *(short8v*)&Bs[row * LDT + ch] = vb;
        }
        __syncthreads();

        short8v af[4], bfr[4];
        #pragma unroll
        for (int i = 0; i < 4; ++i) {
            af[i]  = *(const short8v*)&As[(wm * 64 + i * 16 + lrow) * LDT + kg * 8];
            bfr[i] = *(const short8v*)&Bs[(wn * 64 + i * 16 + lrow) * LDT + kg * 8];
        }
        #pragma unroll
        for (int i = 0; i < 4; ++i)
            #pragma unroll
            for (int j = 0; j < 4; ++j)
                acc[i][j] = __builtin_amdgcn_mfma_f32_16x16x32_bf16(
                    af[i], bfr[j], acc[i][j], 0, 0, 0);
        __syncthreads();
    }

    // D layout: col = lane&15, row = 4*(lane>>4) + reg
    #pragma unroll
    for (int j = 0; j < 4; ++j) {
        int col = n0 + wn * 64 + j * 16 + lrow;
        float bb = bias[col] + res_b[col];
        #pragma unroll
        for (int i = 0; i < 4; ++i) {
            int rbase = m0 + wm * 64 + i * 16 + kg * 4;
            #pragma unroll
            for (int r = 0; r < 4; ++r) {
                int row = rbase + r;
                if (row < N_NODES)
                    out[(size_t)row * FEAT + col] = fmaxf(acc[i][j][r] + bb, 0.f);
            }
        }
    }
}

// ================= fallback fp32 path (only if ws too small) =================
#define BM 64
#define BN 64
#define BK 64
#define LDSS 68

template<int MODE>
__global__ __launch_bounds__(256) void gemm_kernel(
    const float* __restrict__ A, const float* __restrict__ B,
    const float* __restrict__ norm, const float* __restrict__ bias,
    const float* __restrict__ res_b, const float* __restrict__ agg,
    float* __restrict__ C)
{
    __shared__ float A_T[BK][LDSS];
    __shared__ float B_s[BK][LDSS];
    const int t = threadIdx.x;
    const int m0 = blockIdx.x * BM, n0 = blockIdx.y * BN;
    const int tx = t & 15, ty = t >> 4;
    float acc[4][4] = {};
    for (int k0 = 0; k0 < FEAT; k0 += BK) {
        #pragma unroll
        for (int i = 0; i < 4; ++i) {
            int idx = i * 256 + t;
            int m = idx >> 4, k4 = (idx & 15) * 4;
            int row = m0 + m;
            float4 v = make_float4(0.f,0.f,0.f,0.f);
            if (row < N_NODES) v = *(const float4*)&A[(size_t)row * FEAT + k0 + k4];
            A_T[k4+0][m]=v.x; A_T[k4+1][m]=v.y; A_T[k4+2][m]=v.z; A_T[k4+3][m]=v.w;
        }
        #pragma unroll
        for (int i = 0; i < 4; ++i) {
            int idx = i * 256 + t;
            if (MODE == 0) {
                int k = idx >> 4, n4 = (idx & 15) * 4;
                *(float4*)&B_s[k][n4] = *(const float4*)&B[(size_t)(k0+k)*FEAT + n0 + n4];
            } else {
                int n = idx >> 4, k4 = (idx & 15) * 4;
                float4 v = *(const float4*)&B[(size_t)(n0+n)*FEAT + k0 + k4];
                B_s[k4+0][n]=v.x; B_s[k4+1][n]=v.y; B_s[k4+2][n]=v.z; B_s[k4+3][n]=v.w;
            }
        }
        __syncthreads();
        #pragma unroll
        for (int kk = 0; kk < BK; ++kk) {
            float4 av = *(const float4*)&A_T[kk][ty*4];
            float4 bv = *(const float4*)&B_s[kk][tx*4];
            const float a[4]={av.x,av.y,av.z,av.w}, b[4]={bv.x,bv.y,bv.z,bv.w};
            #pragma unroll
            for (int i=0;i<4;++i)
                #pragma unroll
                for (int j=0;j<4;++j) acc[i][j]=fmaf(a[i],b[j],acc[i][j]);
        }
        __syncthreads();
    }
    if (MODE == 0) {
        #pragma unroll
        for (int i=0;i<4;++i) {
            int row=m0+ty*4+i;
            if (row<N_NODES) {
                float nm=norm[row];
                float4 o; o.x=acc[i][0]*nm; o.y=acc[i][1]*nm; o.z=acc[i][2]*nm; o.w=acc[i][3]*nm;
                *(float4*)&C[(size_t)row*FEAT+n0+tx*4]=o;
            }
        }
    } else {
        float4 bv=*(const float4*)&bias[n0+tx*4];
        float4 rb=*(const float4*)&res_b[n0+tx*4];
        #pragma unroll
        for (int i=0;i<4;++i) {
            int row=m0+ty*4+i;
            if (row<N_NODES) {
                float nm=norm[row];
                float4 ag=*(const float4*)&agg[(size_t)row*FEAT+n0+tx*4];
                float4 o;
                o.x=fmaxf(fmaf(ag.x,nm,bv.x)+acc[i][0]+rb.x,0.f);
                o.y=fmaxf(fmaf(ag.y,nm,bv.y)+acc[i][1]+rb.y,0.f);
                o.z=fmaxf(fmaf(ag.z,nm,bv.z)+acc[i][2]+rb.z,0.f);
                o.w=fmaxf(fmaf(ag.w,nm,bv.w)+acc[i][3]+rb.w,0.f);
                *(float4*)&C[(size_t)row*FEAT+n0+tx*4]=o;
            }
        }
    }
}

__global__ __launch_bounds__(256) void scatter_kernel(
    const float* __restrict__ hw, const int* __restrict__ src,
    const int* __restrict__ dst, float* __restrict__ agg)
{
    const int t = threadIdx.x;
    const int e0 = blockIdx.x * 8;
    #pragma unroll
    for (int i = 0; i < 8; ++i) {
        int e = e0 + i;
        if (e < N_EDGES) {
            int s = src[e], d = dst[e];
            atomicAdd(&agg[(size_t)d * FEAT + t], hw[(size_t)s * FEAT + t]);
        }
    }
}

extern "C" void kernel_launch(void* const* d_in, const int* in_sizes, int n_in,
                              void* d_out, int out_size, void* d_ws, size_t ws_size,
                              hipStream_t stream) {
    const float* h      = (const float*)d_in[0];
    const float* norm   = (const float*)d_in[1];
    const int*   src    = (const int*)d_in[2];
    const int*   dst    = (const int*)d_in[3];
    const float* weight = (const float*)d_in[4];
    const float* bias   = (const float*)d_in[5];
    const float* res_w  = (const float*)d_in[6];
    const float* res_b  = (const float*)d_in[7];
    float* out = (float*)d_out;
    char* ws = (char*)d_ws;

    if (ws_size >= WS_NEEDED) {
        unsigned short* xh = (unsigned short*)(ws + OFF_XH);
        unsigned short* Bt = (unsigned short*)(ws + OFF_BT);
        int* seg_cnt  = (int*)(ws + OFF_SEGC);
        int* seg_base = (int*)(ws + OFF_SEGB);
        int* seg_cur  = (int*)(ws + OFF_SEGU);
        unsigned int* bin = (unsigned int*)(ws + OFF_BIN);

        cast_h_kernel<<<N_NODES * FEAT / 8 / 256, 256, 0, stream>>>(h, xh);
        prep_b_kernel<<<256, 256, 0, stream>>>(weight, res_w, Bt);
        hipMemsetAsync(seg_cnt, 0, 8192, stream);
        count_kernel<<<(N_EDGES + 255) / 256, 256, 0, stream>>>(dst, seg_cnt);
        scan_seg_kernel<<<1, 1024, 0, stream>>>(seg_cnt, seg_base, seg_cur);
        bin_kernel<<<(N_EDGES + 255) / 256, 256, 0, stream>>>(src, dst, seg_cur, bin);
        agg_bin_kernel<<<NBUCK, 512, 0, stream>>>(norm, seg_base, bin, xh);
        dim3 gg((N_NODES + GBM - 1) / GBM, FEAT / GBN);
        mfma_gemm_kernel<<<gg, 256, 0, stream>>>(xh, Bt, bias, res_b, out);
    } else {
        float* hw = (float*)ws;
        dim3 gdim((N_NODES + BM - 1) / BM, FEAT / BN);
        gemm_kernel<0><<<gdim, 256, 0, stream>>>(h, weight, norm, nullptr, nullptr, nullptr, hw);
        hipMemsetAsync(out, 0, (size_t)N_NODES * FEAT * sizeof(float), stream);
        scatter_kernel<<<N_EDGES / 8, 256, 0, stream>>>(hw, src, dst, out);
        gemm_kernel<1><<<gdim, 256, 0, stream>>>(h, res_w, norm, bias, res_b, out, out);
    }
}

// Round 8
// 580.967 us; speedup vs baseline: 5.2754x; 5.2754x over previous
//
#include <hip/hip_runtime.h>

#define N_NODES 100000
#define N_EDGES 1600000
#define FEAT 256
#define KTOT 512
#define NBUCK ((N_NODES + 63) / 64)    // 1563 buckets of 64 dst nodes
#define SEGN (NBUCK * 8)               // 12504 sub-segments (8 per bucket)

typedef __attribute__((ext_vector_type(8))) short short8v;     // 8 bf16 = 4 VGPRs
typedef __attribute__((ext_vector_type(4))) float f32x4;
typedef __attribute__((ext_vector_type(4))) unsigned short ushort4v;

__device__ __forceinline__ unsigned short f2bf(float f) {
    unsigned u = __float_as_uint(f);
    return (unsigned short)((u + 0x7FFFu + ((u >> 16) & 1u)) >> 16);   // RNE
}
__device__ __forceinline__ float bf2f(unsigned short s) {
    return __uint_as_float(((unsigned)s) << 16);
}
__device__ __forceinline__ short8v zero8() {
    short8v v;
    #pragma unroll
    for (int i = 0; i < 8; ++i) v[i] = 0;
    return v;
}

// ---------------- workspace layout ----------------
// xh   : [N][512] bf16 — cols 0:256 = z (aggregated), 256:512 = bf16(h)
// Bt   : [256][512] bf16
// segc/segb/segu : sub-segment count/base/cursor (SEGN+1 ints, padded)
// offs : per-node CSR offsets (NBUCK*64+2 ints)
// csr  : [N_EDGES] int (src ids sorted by dst)
// bin  : [N_EDGES] u32 packed ((dst&63)<<20 | src) — lives in d_out (dead before gemm)
constexpr size_t OFF_XH   = 0;
constexpr size_t XH_BYTES = (size_t)N_NODES * KTOT * 2;        // 102,400,000
constexpr size_t OFF_BT   = XH_BYTES;                          // 262,144
constexpr size_t OFF_SEGC = OFF_BT + 262144;
constexpr size_t OFF_SEGB = OFF_SEGC + 51200;
constexpr size_t OFF_SEGU = OFF_SEGB + 51200;
constexpr size_t OFF_OFFS = OFF_SEGU + 51200;
constexpr size_t OFF_CSR  = OFF_OFFS + 400384;
constexpr size_t WS_NEEDED = OFF_CSR + (size_t)N_EDGES * 4;    // 109,616,128 B

__device__ __forceinline__ int seg_of(int d) {   // bucket*8 + (d&7)
    return ((d >> 6) << 3) | (d & 7);
}

// ---------------- prep kernels ----------------
__global__ __launch_bounds__(256) void cast_h_kernel(
    const float* __restrict__ h, unsigned short* __restrict__ xh)
{
    int tid = blockIdx.x * 256 + threadIdx.x;
    int row = tid >> 5;
    int c8  = (tid & 31) * 8;
    const float4* p = (const float4*)&h[(size_t)row * FEAT + c8];
    float4 a = p[0], b = p[1];
    unsigned short tmp[8];
    tmp[0]=f2bf(a.x); tmp[1]=f2bf(a.y); tmp[2]=f2bf(a.z); tmp[3]=f2bf(a.w);
    tmp[4]=f2bf(b.x); tmp[5]=f2bf(b.y); tmp[6]=f2bf(b.z); tmp[7]=f2bf(b.w);
    *(short8v*)&xh[(size_t)row * KTOT + 256 + c8] = *(short8v*)tmp;
}

__global__ __launch_bounds__(256) void prep_b_kernel(
    const float* __restrict__ W, const float* __restrict__ res_w,
    unsigned short* __restrict__ Bt)
{
    int n = blockIdx.x, t = threadIdx.x;
    Bt[(size_t)n * KTOT + t]       = f2bf(W[(size_t)t * FEAT + n]);       // W^T
    Bt[(size_t)n * KTOT + 256 + t] = f2bf(res_w[(size_t)n * FEAT + t]);   // res_w
}

// ---------------- sub-segment binning ----------------
__global__ __launch_bounds__(256) void count_kernel(
    const int* __restrict__ dst, int* __restrict__ segc)
{
    int e = blockIdx.x * 256 + threadIdx.x;
    if (e < N_EDGES) atomicAdd(&segc[seg_of(dst[e])], 1);
}

__global__ __launch_bounds__(1024) void scan_seg_kernel(
    const int* __restrict__ segc,
    int* __restrict__ segb, int* __restrict__ segu)
{
    __shared__ int part[1024];
    const int t = threadIdx.x;
    const int C = (SEGN + 1023) / 1024;        // 13
    const int lo = t * C;
    const int hi = min(lo + C, SEGN);
    int s = 0;
    for (int i = lo; i < hi; ++i) s += segc[i];
    part[t] = s;
    __syncthreads();
    for (int d = 1; d < 1024; d <<= 1) {       // inclusive Hillis-Steele
        int u = (t >= d) ? part[t - d] : 0;
        __syncthreads();
        part[t] += u;
        __syncthreads();
    }
    int prefix = part[t] - s;                  // exclusive
    for (int i = lo; i < hi; ++i) {
        int c = segc[i];
        segb[i] = prefix;
        segu[i] = prefix;
        prefix += c;
    }
    if (t == 0) segb[SEGN] = N_EDGES;
}

__global__ __launch_bounds__(256) void bin_kernel(
    const int* __restrict__ src, const int* __restrict__ dst,
    int* __restrict__ segu, unsigned int* __restrict__ bin)
{
    int e = blockIdx.x * 256 + threadIdx.x;
    if (e < N_EDGES) {
        int d = dst[e];
        int p = atomicAdd(&segu[seg_of(d)], 1);
        bin[p] = ((unsigned)(d & 63) << 20) | (unsigned)src[e];
    }
}

// ---------------- per-bucket counting sort -> csr + offs ----------------
// one block per bucket; bucket range = [segb[b*8], segb[b*8+8]) is contiguous.
__global__ __launch_bounds__(256) void sortcsr_kernel(
    const unsigned int* __restrict__ bin,
    const int* __restrict__ segb,
    int* __restrict__ csr, int* __restrict__ offs)
{
    __shared__ int cnt64[64];
    __shared__ int base64[64];
    __shared__ int cur64[64];
    const int b = blockIdx.x, t = threadIdx.x;
    const int lo = segb[b * 8];
    const int hi = segb[b * 8 + 8];
    if (t < 64) cnt64[t] = 0;
    __syncthreads();
    for (int e = lo + t; e < hi; e += 256)
        atomicAdd(&cnt64[bin[e] >> 20], 1);
    __syncthreads();
    if (t == 0) {
        int acc = 0;
        for (int i = 0; i < 64; ++i) { base64[i] = acc; acc += cnt64[i]; }
    }
    __syncthreads();
    if (t < 64) {
        int o = lo + base64[t];
        offs[b * 64 + t] = o;
        cur64[t] = o;
    }
    __syncthreads();
    for (int e = lo + t; e < hi; e += 256) {
        unsigned pk = bin[e];
        int p = atomicAdd(&cur64[pk >> 20], 1);
        csr[p] = (int)(pk & 0xFFFFF);
    }
    // offs[N_NODES] is written by the last bucket (ln>=32 empty there) -> = N_EDGES
}

// ---------------- aggregate: z[n] = norm[n] * sum_e bf16(h)[src_e]*norm[src_e] ----------------
// proven round-6 kernel: one wave per node, high occupancy, 2-way ILP
__global__ __launch_bounds__(256) void aggregate_kernel(
    const float* __restrict__ norm,
    const int*   __restrict__ offs,
    const int*   __restrict__ csr_src,
    unsigned short* __restrict__ xh)     // reads h half (+256), writes z half
{
    const int wave = threadIdx.x >> 6;
    const int lane = threadIdx.x & 63;
    const int n    = blockIdx.x * 4 + wave;
    if (n >= N_NODES) return;
    const int start = offs[n];
    const int end   = offs[n + 1];
    float a0=0,a1=0,a2=0,a3=0, b0=0,b1=0,b2=0,b3=0;
    int e = start;
    for (; e + 1 < end; e += 2) {
        int s0 = csr_src[e];
        int s1 = csr_src[e + 1];
        float m0 = norm[s0], m1 = norm[s1];
        ushort4v v0 = *(const ushort4v*)&xh[(size_t)s0 * KTOT + 256 + lane * 4];
        ushort4v v1 = *(const ushort4v*)&xh[(size_t)s1 * KTOT + 256 + lane * 4];
        a0 = fmaf(bf2f(v0.x), m0, a0); a1 = fmaf(bf2f(v0.y), m0, a1);
        a2 = fmaf(bf2f(v0.z), m0, a2); a3 = fmaf(bf2f(v0.w), m0, a3);
        b0 = fmaf(bf2f(v1.x), m1, b0); b1 = fmaf(bf2f(v1.y), m1, b1);
        b2 = fmaf(bf2f(v1.z), m1, b2); b3 = fmaf(bf2f(v1.w), m1, b3);
    }
    if (e < end) {
        int s0 = csr_src[e];
        float m0 = norm[s0];
        ushort4v v0 = *(const ushort4v*)&xh[(size_t)s0 * KTOT + 256 + lane * 4];
        a0 = fmaf(bf2f(v0.x), m0, a0); a1 = fmaf(bf2f(v0.y), m0, a1);
        a2 = fmaf(bf2f(v0.z), m0, a2); a3 = fmaf(bf2f(v0.w), m0, a3);
    }
    float nm = norm[n];
    unsigned short tmp[4];
    tmp[0] = f2bf((a0 + b0) * nm);
    tmp[1] = f2bf((a1 + b1) * nm);
    tmp[2] = f2bf((a2 + b2) * nm);
    tmp[3] = f2bf((a3 + b3) * nm);
    *(ushort4v*)&xh[(size_t)n * KTOT + lane * 4] = *(ushort4v*)tmp;
}

// ---------------- fused MFMA GEMM: out = relu(xh @ Bt^T + bias + res_b) ----------------
#define GBM 128
#define GBN 128
#define GBK 32
#define LDT 40   // shorts per LDS row = 80 B

__global__ __launch_bounds__(256) void mfma_gemm_kernel(
    const unsigned short* __restrict__ xh,   // A: [N][512] bf16
    const unsigned short* __restrict__ Bt,   // [256][512] bf16 (n-major)
    const float* __restrict__ bias,
    const float* __restrict__ res_b,
    float* __restrict__ out)
{
    __shared__ unsigned short As[GBM * LDT];
    __shared__ unsigned short Bs[GBN * LDT];
    const int t    = threadIdx.x;
    const int m0   = blockIdx.x * GBM;
    const int n0   = blockIdx.y * GBN;
    const int wave = t >> 6, lane = t & 63;
    const int wm   = wave >> 1, wn = wave & 1;
    const int lrow = lane & 15, kg = lane >> 4;

    f32x4 zf = {0.f, 0.f, 0.f, 0.f};
    f32x4 acc[4][4];
    #pragma unroll
    for (int i = 0; i < 4; ++i)
        #pragma unroll
        for (int j = 0; j < 4; ++j) acc[i][j] = zf;

    for (int k0 = 0; k0 < KTOT; k0 += GBK) {
        #pragma unroll
        for (int it = 0; it < 2; ++it) {
            int idx = it * 256 + t;
            int row = idx >> 2;
            int ch  = (idx & 3) * 8;
            int grow = m0 + row;
            short8v va = zero8();
            if (grow < N_NODES)
                va = *(const short8v*)&xh[(size_t)grow * KTOT + k0 + ch];
            *(short8v*)&As[row * LDT + ch] = va;
            short8v vb = *(const short8v*)&Bt[(size_t)(n0 + row) * KTOT + k0 + ch];
            *(short8v*)&Bs[row * LDT + ch] = vb;
        }
        __syncthreads();

        short8v af[4], bfr[4];
        #pragma unroll
        for (int i = 0; i < 4; ++i) {
            af[i]  = *(const short8v*)&As[(wm * 64 + i * 16 + lrow) * LDT + kg * 8];
            bfr[i] = *(const short8v*)&Bs[(wn * 64 + i * 16 + lrow) * LDT + kg * 8];
        }
        #pragma unroll
        for (int i = 0; i < 4; ++i)
            #pragma unroll
            for (int j = 0; j < 4; ++j)
                acc[i][j] = __builtin_amdgcn_mfma_f32_16x16x32_bf16(
                    af[i], bfr[j], acc[i][j], 0, 0, 0);
        __syncthreads();
    }

    // D layout: col = lane&15, row = 4*(lane>>4) + reg
    #pragma unroll
    for (int j = 0; j < 4; ++j) {
        int col = n0 + wn * 64 + j * 16 + lrow;
        float bb = bias[col] + res_b[col];
        #pragma unroll
        for (int i = 0; i < 4; ++i) {
            int rbase = m0 + wm * 64 + i * 16 + kg * 4;
            #pragma unroll
            for (int r = 0; r < 4; ++r) {
                int row = rbase + r;
                if (row < N_NODES)
                    out[(size_t)row * FEAT + col] = fmaxf(acc[i][j][r] + bb, 0.f);
            }
        }
    }
}

// ================= fallback fp32 path (only if ws too small) =================
#define BM 64
#define BN 64
#define BK 64
#define LDSS 68

template<int MODE>
__global__ __launch_bounds__(256) void gemm_kernel(
    const float* __restrict__ A, const float* __restrict__ B,
    const float* __restrict__ norm, const float* __restrict__ bias,
    const float* __restrict__ res_b, const float* __restrict__ agg,
    float* __restrict__ C)
{
    __shared__ float A_T[BK][LDSS];
    __shared__ float B_s[BK][LDSS];
    const int t = threadIdx.x;
    const int m0 = blockIdx.x * BM, n0 = blockIdx.y * BN;
    const int tx = t & 15, ty = t >> 4;
    float acc[4][4] = {};
    for (int k0 = 0; k0 < FEAT; k0 += BK) {
        #pragma unroll
        for (int i = 0; i < 4; ++i) {
            int idx = i * 256 + t;
            int m = idx >> 4, k4 = (idx & 15) * 4;
            int row = m0 + m;
            float4 v = make_float4(0.f,0.f,0.f,0.f);
            if (row < N_NODES) v = *(const float4*)&A[(size_t)row * FEAT + k0 + k4];
            A_T[k4+0][m]=v.x; A_T[k4+1][m]=v.y; A_T[k4+2][m]=v.z; A_T[k4+3][m]=v.w;
        }
        #pragma unroll
        for (int i = 0; i < 4; ++i) {
            int idx = i * 256 + t;
            if (MODE == 0) {
                int k = idx >> 4, n4 = (idx & 15) * 4;
                *(float4*)&B_s[k][n4] = *(const float4*)&B[(size_t)(k0+k)*FEAT + n0 + n4];
            } else {
                int n = idx >> 4, k4 = (idx & 15) * 4;
                float4 v = *(const float4*)&B[(size_t)(n0+n)*FEAT + k0 + k4];
                B_s[k4+0][n]=v.x; B_s[k4+1][n]=v.y; B_s[k4+2][n]=v.z; B_s[k4+3][n]=v.w;
            }
        }
        __syncthreads();
        #pragma unroll
        for (int kk = 0; kk < BK; ++kk) {
            float4 av = *(const float4*)&A_T[kk][ty*4];
            float4 bv = *(const float4*)&B_s[kk][tx*4];
            const float a[4]={av.x,av.y,av.z,av.w}, b[4]={bv.x,bv.y,bv.z,bv.w};
            #pragma unroll
            for (int i=0;i<4;++i)
                #pragma unroll
                for (int j=0;j<4;++j) acc[i][j]=fmaf(a[i],b[j],acc[i][j]);
        }
        __syncthreads();
    }
    if (MODE == 0) {
        #pragma unroll
        for (int i=0;i<4;++i) {
            int row=m0+ty*4+i;
            if (row<N_NODES) {
                float nm=norm[row];
                float4 o; o.x=acc[i][0]*nm; o.y=acc[i][1]*nm; o.z=acc[i][2]*nm; o.w=acc[i][3]*nm;
                *(float4*)&C[(size_t)row*FEAT+n0+tx*4]=o;
            }
        }
    } else {
        float4 bv=*(const float4*)&bias[n0+tx*4];
        float4 rb=*(const float4*)&res_b[n0+tx*4];
        #pragma unroll
        for (int i=0;i<4;++i) {
            int row=m0+ty*4+i;
            if (row<N_NODES) {
                float nm=norm[row];
                float4 ag=*(const float4*)&agg[(size_t)row*FEAT+n0+tx*4];
                float4 o;
                o.x=fmaxf(fmaf(ag.x,nm,bv.x)+acc[i][0]+rb.x,0.f);
                o.y=fmaxf(fmaf(ag.y,nm,bv.y)+acc[i][1]+rb.y,0.f);
                o.z=fmaxf(fmaf(ag.z,nm,bv.z)+acc[i][2]+rb.z,0.f);
                o.w=fmaxf(fmaf(ag.w,nm,bv.w)+acc[i][3]+rb.w,0.f);
                *(float4*)&C[(size_t)row*FEAT+n0+tx*4]=o;
            }
        }
    }
}

__global__ __launch_bounds__(256) void scatter_kernel(
    const float* __restrict__ hw, const int* __restrict__ src,
    const int* __restrict__ dst, float* __restrict__ agg)
{
    const int t = threadIdx.x;
    const int e0 = blockIdx.x * 8;
    #pragma unroll
    for (int i = 0; i < 8; ++i) {
        int e = e0 + i;
        if (e < N_EDGES) {
            int s = src[e], d = dst[e];
            atomicAdd(&agg[(size_t)d * FEAT + t], hw[(size_t)s * FEAT + t]);
        }
    }
}

extern "C" void kernel_launch(void* const* d_in, const int* in_sizes, int n_in,
                              void* d_out, int out_size, void* d_ws, size_t ws_size,
                              hipStream_t stream) {
    const float* h      = (const float*)d_in[0];
    const float* norm   = (const float*)d_in[1];
    const int*   src    = (const int*)d_in[2];
    const int*   dst    = (const int*)d_in[3];
    const float* weight = (const float*)d_in[4];
    const float* bias   = (const float*)d_in[5];
    const float* res_w  = (const float*)d_in[6];
    const float* res_b  = (const float*)d_in[7];
    float* out = (float*)d_out;
    char* ws = (char*)d_ws;

    if (ws_size >= WS_NEEDED) {
        unsigned short* xh = (unsigned short*)(ws + OFF_XH);
        unsigned short* Bt = (unsigned short*)(ws + OFF_BT);
        int* segc = (int*)(ws + OFF_SEGC);
        int* segb = (int*)(ws + OFF_SEGB);
        int* segu = (int*)(ws + OFF_SEGU);
        int* offs = (int*)(ws + OFF_OFFS);
        int* csr  = (int*)(ws + OFF_CSR);
        unsigned int* bin = (unsigned int*)d_out;   // scratch; fully dead before gemm

        cast_h_kernel<<<N_NODES * FEAT / 8 / 256, 256, 0, stream>>>(h, xh);
        prep_b_kernel<<<256, 256, 0, stream>>>(weight, res_w, Bt);
        hipMemsetAsync(segc, 0, 51200, stream);
        count_kernel<<<(N_EDGES + 255) / 256, 256, 0, stream>>>(dst, segc);
        scan_seg_kernel<<<1, 1024, 0, stream>>>(segc, segb, segu);
        bin_kernel<<<(N_EDGES + 255) / 256, 256, 0, stream>>>(src, dst, segu, bin);
        sortcsr_kernel<<<NBUCK, 256, 0, stream>>>(bin, segb, csr, offs);
        aggregate_kernel<<<(N_NODES + 3) / 4, 256, 0, stream>>>(norm, offs, csr, xh);
        dim3 gg((N_NODES + GBM - 1) / GBM, FEAT / GBN);
        mfma_gemm_kernel<<<gg, 256, 0, stream>>>(xh, Bt, bias, res_b, out);
    } else {
        float* hw = (float*)ws;
        dim3 gdim((N_NODES + BM - 1) / BM, FEAT / BN);
        gemm_kernel<0><<<gdim, 256, 0, stream>>>(h, weight, norm, nullptr, nullptr, nullptr, hw);
        hipMemsetAsync(out, 0, (size_t)N_NODES * FEAT * sizeof(float), stream);
        scatter_kernel<<<N_EDGES / 8, 256, 0, stream>>>(hw, src, dst, out);
        gemm_kernel<1><<<gdim, 256, 0, stream>>>(h, res_w, norm, bias, res_b, out, out);
    }
}

// Round 9
// 567.906 us; speedup vs baseline: 5.3967x; 1.0230x over previous
//
#include <hip/hip_runtime.h>

#define N_NODES 100000
#define N_EDGES 1600000
#define FEAT 256
#define KTOT 512
#define NBUCK ((N_NODES + 63) / 64)    // 1563 buckets of 64 dst nodes
#define SEGN (NBUCK * 8)               // 12504 sub-segments (8 per bucket)
#define CAST_BLOCKS 12500
#define COUNT_BLOCKS 6250
#define SCANB 13                       // ceil(SEGN/1024)

typedef __attribute__((ext_vector_type(8))) short short8v;     // 8 bf16 = 4 VGPRs
typedef __attribute__((ext_vector_type(4))) float f32x4;
typedef __attribute__((ext_vector_type(4))) unsigned short ushort4v;

__device__ __forceinline__ unsigned short f2bf(float f) {
    unsigned u = __float_as_uint(f);
    return (unsigned short)((u + 0x7FFFu + ((u >> 16) & 1u)) >> 16);   // RNE
}
__device__ __forceinline__ float bf2f(unsigned short s) {
    return __uint_as_float(((unsigned)s) << 16);
}
__device__ __forceinline__ short8v zero8() {
    short8v v;
    #pragma unroll
    for (int i = 0; i < 8; ++i) v[i] = 0;
    return v;
}

// ---------------- workspace layout ----------------
constexpr size_t OFF_XH   = 0;
constexpr size_t XH_BYTES = (size_t)N_NODES * KTOT * 2;        // 102,400,000
constexpr size_t OFF_BT   = XH_BYTES;
constexpr size_t OFF_SEGC = OFF_BT + 262144;
constexpr size_t OFF_SEGB = OFF_SEGC + 51200;
constexpr size_t OFF_SEGU = OFF_SEGB + 51200;
constexpr size_t OFF_OFFS = OFF_SEGU + 51200;
constexpr size_t OFF_BSUM = OFF_OFFS + 400384;
constexpr size_t OFF_CSR  = OFF_BSUM + 1024;
constexpr size_t WS_NEEDED = OFF_CSR + (size_t)N_EDGES * 4;

__device__ __forceinline__ int seg_of(int d) {   // bucket*8 + (d&7)
    return ((d >> 6) << 3) | (d & 7);
}

// ---------------- fused prep: cast_h || count || prep_b (independent phases) ----------------
__global__ __launch_bounds__(256) void prep_count_kernel(
    const float* __restrict__ h, const float* __restrict__ W,
    const float* __restrict__ res_w, const int* __restrict__ dst,
    unsigned short* __restrict__ xh, unsigned short* __restrict__ Bt,
    int* __restrict__ segc)
{
    const int bid = blockIdx.x, t = threadIdx.x;
    if (bid < CAST_BLOCKS) {
        int tid = bid * 256 + t;
        int row = tid >> 5;
        int c8  = (tid & 31) * 8;
        const float4* p = (const float4*)&h[(size_t)row * FEAT + c8];
        float4 a = p[0], b = p[1];
        unsigned short tmp[8];
        tmp[0]=f2bf(a.x); tmp[1]=f2bf(a.y); tmp[2]=f2bf(a.z); tmp[3]=f2bf(a.w);
        tmp[4]=f2bf(b.x); tmp[5]=f2bf(b.y); tmp[6]=f2bf(b.z); tmp[7]=f2bf(b.w);
        *(short8v*)&xh[(size_t)row * KTOT + 256 + c8] = *(short8v*)tmp;
    } else if (bid < CAST_BLOCKS + COUNT_BLOCKS) {
        int e = (bid - CAST_BLOCKS) * 256 + t;    // exactly covers N_EDGES
        atomicAdd(&segc[seg_of(dst[e])], 1);
    } else {
        int n = bid - (CAST_BLOCKS + COUNT_BLOCKS);
        Bt[(size_t)n * KTOT + t]       = f2bf(W[(size_t)t * FEAT + n]);
        Bt[(size_t)n * KTOT + 256 + t] = f2bf(res_w[(size_t)n * FEAT + t]);
    }
}

// ---------------- 3-phase parallel scan over SEGN sub-segment counts ----------------
__global__ __launch_bounds__(1024) void segscan_p1(
    const int* __restrict__ segc, int* __restrict__ bsum)
{
    __shared__ int red[1024];
    int i = blockIdx.x * 1024 + threadIdx.x;
    red[threadIdx.x] = (i < SEGN) ? segc[i] : 0;
    __syncthreads();
    #pragma unroll
    for (int d = 512; d > 0; d >>= 1) {
        if (threadIdx.x < d) red[threadIdx.x] += red[threadIdx.x + d];
        __syncthreads();
    }
    if (threadIdx.x == 0) bsum[blockIdx.x] = red[0];
}

__global__ __launch_bounds__(64) void segscan_p2(int* __restrict__ bsum)
{
    if (threadIdx.x == 0) {
        int acc = 0;
        for (int i = 0; i < SCANB; ++i) { int c = bsum[i]; bsum[i] = acc; acc += c; }
    }
}

__global__ __launch_bounds__(1024) void segscan_p3(
    const int* __restrict__ segc, const int* __restrict__ bsum,
    int* __restrict__ segb, int* __restrict__ segu)
{
    __shared__ int part[1024];
    const int b = blockIdx.x, t = threadIdx.x;
    const int i = b * 1024 + t;
    int v = (i < SEGN) ? segc[i] : 0;
    part[t] = v;
    __syncthreads();
    for (int d = 1; d < 1024; d <<= 1) {      // inclusive Hillis-Steele
        int u = (t >= d) ? part[t - d] : 0;
        __syncthreads();
        part[t] += u;
        __syncthreads();
    }
    int ex = bsum[b] + part[t] - v;           // exclusive prefix
    if (i < SEGN) { segb[i] = ex; segu[i] = ex; }
    if (i == SEGN) segb[SEGN] = N_EDGES;
}

// ---------------- bin + per-bucket counting sort ----------------
__global__ __launch_bounds__(256) void bin_kernel(
    const int* __restrict__ src, const int* __restrict__ dst,
    int* __restrict__ segu, unsigned int* __restrict__ bin)
{
    int e = blockIdx.x * 256 + threadIdx.x;
    if (e < N_EDGES) {
        int d = dst[e];
        int p = atomicAdd(&segu[seg_of(d)], 1);
        bin[p] = ((unsigned)(d & 63) << 20) | (unsigned)src[e];
    }
}

__global__ __launch_bounds__(256) void sortcsr_kernel(
    const unsigned int* __restrict__ bin,
    const int* __restrict__ segb,
    int* __restrict__ csr, int* __restrict__ offs)
{
    __shared__ int cnt64[64];
    __shared__ int base64[64];
    __shared__ int cur64[64];
    const int b = blockIdx.x, t = threadIdx.x;
    const int lo = segb[b * 8];
    const int hi = segb[b * 8 + 8];
    if (t < 64) cnt64[t] = 0;
    __syncthreads();
    for (int e = lo + t; e < hi; e += 256)
        atomicAdd(&cnt64[bin[e] >> 20], 1);
    __syncthreads();
    if (t == 0) {
        int acc = 0;
        for (int i = 0; i < 64; ++i) { base64[i] = acc; acc += cnt64[i]; }
    }
    __syncthreads();
    if (t < 64) {
        int o = lo + base64[t];
        offs[b * 64 + t] = o;
        cur64[t] = o;
    }
    __syncthreads();
    for (int e = lo + t; e < hi; e += 256) {
        unsigned pk = bin[e];
        int p = atomicAdd(&cur64[pk >> 20], 1);
        csr[p] = (int)(pk & 0xFFFFF);
    }
}

// ---------------- aggregate: z[n] = norm[n] * sum_e bf16(h)[src_e]*norm[src_e] ----------------
// one wave per node; 4-edge ILP
__global__ __launch_bounds__(256) void aggregate_kernel(
    const float* __restrict__ norm,
    const int*   __restrict__ offs,
    const int*   __restrict__ csr_src,
    unsigned short* __restrict__ xh)
{
    const int wave = threadIdx.x >> 6;
    const int lane = threadIdx.x & 63;
    const int n    = blockIdx.x * 4 + wave;
    if (n >= N_NODES) return;
    const int start = offs[n];
    const int end   = offs[n + 1];
    float a0=0,a1=0,a2=0,a3=0;
    float b0=0,b1=0,b2=0,b3=0;
    float c0=0,c1=0,c2=0,c3=0;
    float d0=0,d1=0,d2=0,d3=0;
    int e = start;
    for (; e + 3 < end; e += 4) {
        int s0 = csr_src[e], s1 = csr_src[e+1], s2 = csr_src[e+2], s3 = csr_src[e+3];
        float m0 = norm[s0], m1 = norm[s1], m2 = norm[s2], m3 = norm[s3];
        ushort4v v0 = *(const ushort4v*)&xh[(size_t)s0 * KTOT + 256 + lane * 4];
        ushort4v v1 = *(const ushort4v*)&xh[(size_t)s1 * KTOT + 256 + lane * 4];
        ushort4v v2 = *(const ushort4v*)&xh[(size_t)s2 * KTOT + 256 + lane * 4];
        ushort4v v3 = *(const ushort4v*)&xh[(size_t)s3 * KTOT + 256 + lane * 4];
        a0 = fmaf(bf2f(v0.x), m0, a0); a1 = fmaf(bf2f(v0.y), m0, a1);
        a2 = fmaf(bf2f(v0.z), m0, a2); a3 = fmaf(bf2f(v0.w), m0, a3);
        b0 = fmaf(bf2f(v1.x), m1, b0); b1 = fmaf(bf2f(v1.y), m1, b1);
        b2 = fmaf(bf2f(v1.z), m1, b2); b3 = fmaf(bf2f(v1.w), m1, b3);
        c0 = fmaf(bf2f(v2.x), m2, c0); c1 = fmaf(bf2f(v2.y), m2, c1);
        c2 = fmaf(bf2f(v2.z), m2, c2); c3 = fmaf(bf2f(v2.w), m2, c3);
        d0 = fmaf(bf2f(v3.x), m3, d0); d1 = fmaf(bf2f(v3.y), m3, d1);
        d2 = fmaf(bf2f(v3.z), m3, d2); d3 = fmaf(bf2f(v3.w), m3, d3);
    }
    for (; e < end; ++e) {
        int s0 = csr_src[e];
        float m0 = norm[s0];
        ushort4v v0 = *(const ushort4v*)&xh[(size_t)s0 * KTOT + 256 + lane * 4];
        a0 = fmaf(bf2f(v0.x), m0, a0); a1 = fmaf(bf2f(v0.y), m0, a1);
        a2 = fmaf(bf2f(v0.z), m0, a2); a3 = fmaf(bf2f(v0.w), m0, a3);
    }
    float nm = norm[n];
    unsigned short tmp[4];
    tmp[0] = f2bf(((a0 + b0) + (c0 + d0)) * nm);
    tmp[1] = f2bf(((a1 + b1) + (c1 + d1)) * nm);
    tmp[2] = f2bf(((a2 + b2) + (c2 + d2)) * nm);
    tmp[3] = f2bf(((a3 + b3) + (c3 + d3)) * nm);
    *(ushort4v*)&xh[(size_t)n * KTOT + lane * 4] = *(ushort4v*)tmp;
}

// ---------------- fused MFMA GEMM (single pass over xh): out = relu(xh @ Bt^T + bias + res_b) ----------------
// block tile 128 x 256 (all cols), 4 waves 2x2 -> wave tile 64 rows x 128 cols
#define GBM 128
#define GBN2 256
#define GBK 32
#define LDT 40   // shorts per LDS row = 80 B

__global__ __launch_bounds__(256) void mfma_gemm_kernel(
    const unsigned short* __restrict__ xh,   // A: [N][512] bf16
    const unsigned short* __restrict__ Bt,   // [256][512] bf16 (n-major)
    const float* __restrict__ bias,
    const float* __restrict__ res_b,
    float* __restrict__ out)
{
    __shared__ unsigned short As[GBM * LDT];    // 10 KB
    __shared__ unsigned short Bs[GBN2 * LDT];   // 20 KB
    const int t    = threadIdx.x;
    const int m0   = blockIdx.x * GBM;
    const int wave = t >> 6, lane = t & 63;
    const int wm   = wave >> 1, wn = wave & 1;
    const int lrow = lane & 15, kg = lane >> 4;

    f32x4 zf = {0.f, 0.f, 0.f, 0.f};
    f32x4 acc[4][8];
    #pragma unroll
    for (int i = 0; i < 4; ++i)
        #pragma unroll
        for (int j = 0; j < 8; ++j) acc[i][j] = zf;

    for (int k0 = 0; k0 < KTOT; k0 += GBK) {
        #pragma unroll
        for (int it = 0; it < 2; ++it) {         // A: 128 rows x 4 chunks
            int idx = it * 256 + t;
            int row = idx >> 2;
            int ch  = (idx & 3) * 8;
            int grow = m0 + row;
            short8v va = zero8();
            if (grow < N_NODES)
                va = *(const short8v*)&xh[(size_t)grow * KTOT + k0 + ch];
            *(short8v*)&As[row * LDT + ch] = va;
        }
        #pragma unroll
        for (int it = 0; it < 4; ++it) {         // B: 256 rows x 4 chunks
            int idx = it * 256 + t;
            int row = idx >> 2;
            int ch  = (idx & 3) * 8;
            short8v vb = *(const short8v*)&Bt[(size_t)row * KTOT + k0 + ch];
            *(short8v*)&Bs[row * LDT + ch] = vb;
        }
        __syncthreads();

        short8v af[4], bfr[8];
        #pragma unroll
        for (int i = 0; i < 4; ++i)
            af[i] = *(const short8v*)&As[(wm * 64 + i * 16 + lrow) * LDT + kg * 8];
        #pragma unroll
        for (int j = 0; j < 8; ++j)
            bfr[j] = *(const short8v*)&Bs[(wn * 128 + j * 16 + lrow) * LDT + kg * 8];
        #pragma unroll
        for (int i = 0; i < 4; ++i)
            #pragma unroll
            for (int j = 0; j < 8; ++j)
                acc[i][j] = __builtin_amdgcn_mfma_f32_16x16x32_bf16(
                    af[i], bfr[j], acc[i][j], 0, 0, 0);
        __syncthreads();
    }

    // D layout: col = lane&15, row = 4*(lane>>4) + reg
    #pragma unroll
    for (int j = 0; j < 8; ++j) {
        int col = wn * 128 + j * 16 + lrow;
        float bb = bias[col] + res_b[col];
        #pragma unroll
        for (int i = 0; i < 4; ++i) {
            int rbase = m0 + wm * 64 + i * 16 + kg * 4;
            #pragma unroll
            for (int r = 0; r < 4; ++r) {
                int row = rbase + r;
                if (row < N_NODES)
                    out[(size_t)row * FEAT + col] = fmaxf(acc[i][j][r] + bb, 0.f);
            }
        }
    }
}

// ================= fallback fp32 path (only if ws too small) =================
#define BM 64
#define BN 64
#define BK 64
#define LDSS 68

template<int MODE>
__global__ __launch_bounds__(256) void gemm_kernel(
    const float* __restrict__ A, const float* __restrict__ B,
    const float* __restrict__ norm, const float* __restrict__ bias,
    const float* __restrict__ res_b, const float* __restrict__ agg,
    float* __restrict__ C)
{
    __shared__ float A_T[BK][LDSS];
    __shared__ float B_s[BK][LDSS];
    const int t = threadIdx.x;
    const int m0 = blockIdx.x * BM, n0 = blockIdx.y * BN;
    const int tx = t & 15, ty = t >> 4;
    float acc[4][4] = {};
    for (int k0 = 0; k0 < FEAT; k0 += BK) {
        #pragma unroll
        for (int i = 0; i < 4; ++i) {
            int idx = i * 256 + t;
            int m = idx >> 4, k4 = (idx & 15) * 4;
            int row = m0 + m;
            float4 v = make_float4(0.f,0.f,0.f,0.f);
            if (row < N_NODES) v = *(const float4*)&A[(size_t)row * FEAT + k0 + k4];
            A_T[k4+0][m]=v.x; A_T[k4+1][m]=v.y; A_T[k4+2][m]=v.z; A_T[k4+3][m]=v.w;
        }
        #pragma unroll
        for (int i = 0; i < 4; ++i) {
            int idx = i * 256 + t;
            if (MODE == 0) {
                int k = idx >> 4, n4 = (idx & 15) * 4;
                *(float4*)&B_s[k][n4] = *(const float4*)&B[(size_t)(k0+k)*FEAT + n0 + n4];
            } else {
                int n = idx >> 4, k4 = (idx & 15) * 4;
                float4 v = *(const float4*)&B[(size_t)(n0+n)*FEAT + k0 + k4];
                B_s[k4+0][n]=v.x; B_s[k4+1][n]=v.y; B_s[k4+2][n]=v.z; B_s[k4+3][n]=v.w;
            }
        }
        __syncthreads();
        #pragma unroll
        for (int kk = 0; kk < BK; ++kk) {
            float4 av = *(const float4*)&A_T[kk][ty*4];
            float4 bv = *(const float4*)&B_s[kk][tx*4];
            const float a[4]={av.x,av.y,av.z,av.w}, b[4]={bv.x,bv.y,bv.z,bv.w};
            #pragma unroll
            for (int i=0;i<4;++i)
                #pragma unroll
                for (int j=0;j<4;++j) acc[i][j]=fmaf(a[i],b[j],acc[i][j]);
        }
        __syncthreads();
    }
    if (MODE == 0) {
        #pragma unroll
        for (int i=0;i<4;++i) {
            int row=m0+ty*4+i;
            if (row<N_NODES) {
                float nm=norm[row];
                float4 o; o.x=acc[i][0]*nm; o.y=acc[i][1]*nm; o.z=acc[i][2]*nm; o.w=acc[i][3]*nm;
                *(float4*)&C[(size_t)row*FEAT+n0+tx*4]=o;
            }
        }
    } else {
        float4 bv=*(const float4*)&bias[n0+tx*4];
        float4 rb=*(const float4*)&res_b[n0+tx*4];
        #pragma unroll
        for (int i=0;i<4;++i) {
            int row=m0+ty*4+i;
            if (row<N_NODES) {
                float nm=norm[row];
                float4 ag=*(const float4*)&agg[(size_t)row*FEAT+n0+tx*4];
                float4 o;
                o.x=fmaxf(fmaf(ag.x,nm,bv.x)+acc[i][0]+rb.x,0.f);
                o.y=fmaxf(fmaf(ag.y,nm,bv.y)+acc[i][1]+rb.y,0.f);
                o.z=fmaxf(fmaf(ag.z,nm,bv.z)+acc[i][2]+rb.z,0.f);
                o.w=fmaxf(fmaf(ag.w,nm,bv.w)+acc[i][3]+rb.w,0.f);
                *(float4*)&C[(size_t)row*FEAT+n0+tx*4]=o;
            }
        }
    }
}

__global__ __launch_bounds__(256) void scatter_kernel(
    const float* __restrict__ hw, const int* __restrict__ src,
    const int* __restrict__ dst, float* __restrict__ agg)
{
    const int t = threadIdx.x;
    const int e0 = blockIdx.x * 8;
    #pragma unroll
    for (int i = 0; i < 8; ++i) {
        int e = e0 + i;
        if (e < N_EDGES) {
            int s = src[e], d = dst[e];
            atomicAdd(&agg[(size_t)d * FEAT + t], hw[(size_t)s * FEAT + t]);
        }
    }
}

extern "C" void kernel_launch(void* const* d_in, const int* in_sizes, int n_in,
                              void* d_out, int out_size, void* d_ws, size_t ws_size,
                              hipStream_t stream) {
    const float* h      = (const float*)d_in[0];
    const float* norm   = (const float*)d_in[1];
    const int*   src    = (const int*)d_in[2];
    const int*   dst    = (const int*)d_in[3];
    const float* weight = (const float*)d_in[4];
    const float* bias   = (const float*)d_in[5];
    const float* res_w  = (const float*)d_in[6];
    const float* res_b  = (const float*)d_in[7];
    float* out = (float*)d_out;
    char* ws = (char*)d_ws;

    if (ws_size >= WS_NEEDED) {
        unsigned short* xh = (unsigned short*)(ws + OFF_XH);
        unsigned short* Bt = (unsigned short*)(ws + OFF_BT);
        int* segc = (int*)(ws + OFF_SEGC);
        int* segb = (int*)(ws + OFF_SEGB);
        int* segu = (int*)(ws + OFF_SEGU);
        int* offs = (int*)(ws + OFF_OFFS);
        int* bsum = (int*)(ws + OFF_BSUM);
        int* csr  = (int*)(ws + OFF_CSR);
        unsigned int* bin = (unsigned int*)d_out;   // scratch; dead before gemm

        hipMemsetAsync(segc, 0, 51200, stream);
        prep_count_kernel<<<CAST_BLOCKS + COUNT_BLOCKS + 256, 256, 0, stream>>>(
            h, weight, res_w, dst, xh, Bt, segc);
        segscan_p1<<<SCANB, 1024, 0, stream>>>(segc, bsum);
        segscan_p2<<<1, 64, 0, stream>>>(bsum);
        segscan_p3<<<SCANB, 1024, 0, stream>>>(segc, bsum, segb, segu);
        bin_kernel<<<(N_EDGES + 255) / 256, 256, 0, stream>>>(src, dst, segu, bin);
        sortcsr_kernel<<<NBUCK, 256, 0, stream>>>(bin, segb, csr, offs);
        aggregate_kernel<<<(N_NODES + 3) / 4, 256, 0, stream>>>(norm, offs, csr, xh);
        mfma_gemm_kernel<<<(N_NODES + GBM - 1) / GBM, 256, 0, stream>>>(
            xh, Bt, bias, res_b, out);
    } else {
        float* hw = (float*)ws;
        dim3 gdim((N_NODES + BM - 1) / BM, FEAT / BN);
        gemm_kernel<0><<<gdim, 256, 0, stream>>>(h, weight, norm, nullptr, nullptr, nullptr, hw);
        hipMemsetAsync(out, 0, (size_t)N_NODES * FEAT * sizeof(float), stream);
        scatter_kernel<<<N_EDGES / 8, 256, 0, stream>>>(hw, src, dst, out);
        gemm_kernel<1><<<gdim, 256, 0, stream>>>(h, res_w, norm, bias, res_b, out, out);
    }
}